// Round 6
// baseline (216.067 us; speedup 1.0000x reference)
//
#include <hip/hip_runtime.h>
#include <hip/hip_fp16.h>

// Problem constants (match reference)
#define V_ 100000
#define D_ 256
#define M_ 4096
#define C_ 4096
#define L_ 32
#define ROWS_MEMS (M_ + 1)          // 4097 rows in mems_enc (mems + xs_emb)
#define NTASK (1 + M_ + 1 + C_)     // 8194 encode row-tasks

#define LT_ELEMS ((size_t)V_ * D_)              // 25.6M
#define HALF_TBL_OFF 8192                        // byte offset of fp16 table in ws
#define WS_NEEDED (HALF_TBL_OFF + LT_ELEMS * 2)  // ~51.2 MB
// ws float layout: lhs_raw[256] | gsum[1] | g_xs[257] (xf[256], an2) | pad | fp16 tbl

__device__ __forceinline__ float wave_allreduce_sum(float v) {
    #pragma unroll
    for (int off = 32; off >= 1; off >>= 1) v += __shfl_xor(v, off, 64);
    return v;
}

__device__ __forceinline__ float lane_bcast_f(float v, int l) {
    return __uint_as_float((unsigned)__builtin_amdgcn_readlane((int)__float_as_uint(v), l));
}

// ---------------------------------------------------------------------------
// K-1: one-wave xs encode (fp32, full precision) -> g_xs[0..255] + an2 at [256].
// Removes the serial wave-0 xs prologue from the 1025 att blocks (it doubled
// their critical path). Also zeroes lhs_raw/gsum so the memset dispatch goes.
// ---------------------------------------------------------------------------
__global__ __launch_bounds__(64) void xs_pre(
    const int* __restrict__ xs, const float* __restrict__ lt,
    const float* __restrict__ freqs, float* __restrict__ lhs_raw,
    float* __restrict__ gsum, float* __restrict__ g_xs)
{
    const int lane = threadIdx.x;
    // zero the accumulators (replaces hipMemsetAsync)
    *reinterpret_cast<float4*>(lhs_raw + lane * 4) = make_float4(0.f, 0.f, 0.f, 0.f);
    if (lane == 0) *gsum = 0.f;

    int tok = 0; float w = 0.f;
    if (lane < L_) { tok = xs[lane]; w = freqs[tok]; }
    const float s2 = wave_allreduce_sum(w * w);
    const float wn = w / sqrtf(s2);

    const char* ltb = (const char*)lt;
    const unsigned voff = (unsigned)lane * 16u;
    float4 acc = make_float4(0.f, 0.f, 0.f, 0.f);
    #pragma unroll
    for (int lb = 0; lb < L_; lb += 8) {
        float4 v[8];
        #pragma unroll
        for (int j = 0; j < 8; ++j) {
            const unsigned t = (unsigned)__builtin_amdgcn_readlane(tok, lb + j);
            v[j] = *reinterpret_cast<const float4*>(ltb + t * 1024u + voff);
        }
        #pragma unroll
        for (int j = 0; j < 8; ++j) {
            const float wl = lane_bcast_f(wn, lb + j);
            acc.x = fmaf(wl, v[j].x, acc.x);
            acc.y = fmaf(wl, v[j].y, acc.y);
            acc.z = fmaf(wl, v[j].z, acc.z);
            acc.w = fmaf(wl, v[j].w, acc.w);
        }
    }
    *reinterpret_cast<float4*>(g_xs + lane * 4) = acc;
    const float an2 = wave_allreduce_sum(acc.x*acc.x + acc.y*acc.y + acc.z*acc.z + acc.w*acc.w);
    if (lane == 0) g_xs[256] = an2;
}

// ---------------------------------------------------------------------------
// K0: stream-convert lt fp32 -> fp16 (prereq for the 2-rows-per-load gather).
// ---------------------------------------------------------------------------
__global__ __launch_bounds__(256) void convert_lt(
    const float4* __restrict__ src, uint2* __restrict__ dst, int n4)
{
    for (int i = blockIdx.x * blockDim.x + threadIdx.x; i < n4;
         i += gridDim.x * blockDim.x) {
        const float4 v = src[i];
        const __half2 h0 = __floats2half2_rn(v.x, v.y);
        const __half2 h1 = __floats2half2_rn(v.z, v.w);
        dst[i] = make_uint2(*(const unsigned*)&h0, *(const unsigned*)&h1);
    }
}

// ---------------------------------------------------------------------------
// K1 fast path: fused encode + attention, TWO token rows per load instruction.
//   fp16 row = 512 B = 32 lanes x dwordx4, so lanes 0-31 fetch token 2j and
//   lanes 32-63 fetch token 2j+1 in ONE global_load_dwordx4 -> 16 gather
//   instructions per row instead of 32. Evidence (r0/r2/r5): time tracks
//   instruction count, not bytes, lines, or per-wave in-flight depth.
//   Lane l holds dims [8*(l&31), +8) of its half's tokens; one shfl_xor(32)
//   pass merges even/odd-token partials so both lanes of a pair hold the
//   full 8-dim sums (allreduce dot products carry a 0.5x factor).
// ---------------------------------------------------------------------------
__global__ __launch_bounds__(256) void encode_fused_h16(
    const int* __restrict__ xs, const int* __restrict__ mems,
    const int* __restrict__ ys, const int* __restrict__ cands,
    const char* __restrict__ lth, const float* __restrict__ freqs,
    const float* __restrict__ g_xs,
    float* __restrict__ lhs_raw, float* __restrict__ gsum,
    float* __restrict__ out_ys)
{
    __shared__ float s_xf[D_];
    __shared__ float s_lred[D_];
    __shared__ float s_ered;
    __shared__ float s_an2;

    const int tid  = threadIdx.x;
    const int wave = tid >> 6;
    const int lane = tid & 63;
    const int rt0 = blockIdx.x * 4;
    const bool block_has_att = (rt0 <= M_);

    s_lred[tid] = 0.f;
    if (tid == 0) s_ered = 0.f;
    if (block_has_att) {
        s_xf[tid] = g_xs[tid];              // xs encoding, precomputed fp32
        if (tid == 0) s_an2 = g_xs[256];
    }
    __syncthreads();

    const int rt = rt0 + wave;
    if (rt < NTASK) {
        const int* tok_ptr; float* dst = nullptr; bool has_att = false;
        if (rt == 0) {                       // xs row itself
            tok_ptr = xs; has_att = true;
        } else if (rt <= M_) {               // mems row rt-1
            tok_ptr = mems + (size_t)(rt - 1) * L_; has_att = true;
        } else if (rt == M_ + 1) {           // ys -> out_ys row 0
            tok_ptr = ys; dst = out_ys;
        } else {                             // cands -> out_ys rows 1..4096
            const int c = rt - (M_ + 2);
            tok_ptr = cands + (size_t)c * L_;
            dst = out_ys + (size_t)(c + 1) * D_;
        }

        int tok = 0; float w = 0.f;
        if (lane < L_) { tok = tok_ptr[lane]; w = freqs[tok]; }
        const float s2 = wave_allreduce_sum(w * w);
        const float wn = w / sqrtf(s2);      // freqs > 0 -> s2 > 0

        const bool lo = (lane < 32);
        const unsigned inner = (unsigned)(lane & 31) * 16u;

        float acc[8] = {0.f,0.f,0.f,0.f,0.f,0.f,0.f,0.f};
        #pragma unroll
        for (int jb = 0; jb < 16; jb += 8) {
            uint4 v[8];
            #pragma unroll
            for (int j = 0; j < 8; ++j) {
                const unsigned ta = (unsigned)__builtin_amdgcn_readlane(tok, 2*(jb+j));
                const unsigned tb = (unsigned)__builtin_amdgcn_readlane(tok, 2*(jb+j)+1);
                const unsigned row = lo ? ta : tb;   // cndmask between two SGPRs
                v[j] = *reinterpret_cast<const uint4*>(lth + row * 512u + inner);
            }
            #pragma unroll
            for (int j = 0; j < 8; ++j) {
                const float wa = lane_bcast_f(wn, 2*(jb+j));
                const float wb = lane_bcast_f(wn, 2*(jb+j)+1);
                const float wl = lo ? wa : wb;
                const __half2* h = reinterpret_cast<const __half2*>(&v[j]);
                #pragma unroll
                for (int k = 0; k < 4; ++k) {
                    const float2 f = __half22float2(h[k]);
                    acc[2*k]   = fmaf(wl, f.x, acc[2*k]);
                    acc[2*k+1] = fmaf(wl, f.y, acc[2*k+1]);
                }
            }
        }
        // merge even-token (lanes<32) and odd-token (lanes>=32) partials:
        // afterwards BOTH lanes of a pair hold the full 8-dim sums
        #pragma unroll
        for (int k = 0; k < 8; ++k) acc[k] += __shfl_xor(acc[k], 32, 64);

        const int bq = 8 * (lane & 31);          // pair's dim base
        const int bs = bq + (lo ? 0 : 4);        // this lane's 4-dim slice
        const float o0 = lo ? acc[0] : acc[4];   // static indices (no scratch)
        const float o1 = lo ? acc[1] : acc[5];
        const float o2 = lo ? acc[2] : acc[6];
        const float o3 = lo ? acc[3] : acc[7];

        if (has_att) {
            const float4 xf0 = *reinterpret_cast<const float4*>(&s_xf[bq]);
            const float4 xf1 = *reinterpret_cast<const float4*>(&s_xf[bq + 4]);
            const float pd = acc[0]*xf0.x + acc[1]*xf0.y + acc[2]*xf0.z + acc[3]*xf0.w
                           + acc[4]*xf1.x + acc[5]*xf1.y + acc[6]*xf1.z + acc[7]*xf1.w;
            const float pq = acc[0]*acc[0] + acc[1]*acc[1] + acc[2]*acc[2] + acc[3]*acc[3]
                           + acc[4]*acc[4] + acc[5]*acc[5] + acc[6]*acc[6] + acc[7]*acc[7];
            const float d = 0.5f * wave_allreduce_sum(pd);   // dims counted twice
            const float q = 0.5f * wave_allreduce_sum(pq);
            const float an = fmaxf(sqrtf(s_an2), 1e-8f);
            const float bn = fmaxf(sqrtf(q),  1e-8f);
            const float e = expf(d / (an * bn));             // cos in [-1,1]
            atomicAdd(&s_lred[bs + 0], e * o0);
            atomicAdd(&s_lred[bs + 1], e * o1);
            atomicAdd(&s_lred[bs + 2], e * o2);
            atomicAdd(&s_lred[bs + 3], e * o3);
            if (lane == 0) atomicAdd(&s_ered, e);
        } else {
            *reinterpret_cast<float4*>(dst + bs) = make_float4(o0, o1, o2, o3);
        }
    }

    if (block_has_att) {
        __syncthreads();
        atomicAdd(&lhs_raw[tid], s_lred[tid]);
        if (tid == 0) atomicAdd(gsum, s_ered);
    }
}

// ---------------------------------------------------------------------------
// Fallback (ws too small for fp16 table): round-2 fp32 kernel, self-contained.
// ---------------------------------------------------------------------------
__device__ __forceinline__ float4 encode_row_f(const int* __restrict__ tok_ptr,
                                               const char* __restrict__ ltb,
                                               const float* __restrict__ freqs,
                                               const int lane, const unsigned voff) {
    int tok = 0; float w = 0.f;
    if (lane < L_) { tok = tok_ptr[lane]; w = freqs[tok]; }
    const float s2 = wave_allreduce_sum(w * w);
    const float wn = w / sqrtf(s2);
    float4 acc = make_float4(0.f, 0.f, 0.f, 0.f);
    #pragma unroll
    for (int lb = 0; lb < L_; lb += 8) {
        float4 v[8];
        #pragma unroll
        for (int j = 0; j < 8; ++j) {
            const unsigned t = (unsigned)__builtin_amdgcn_readlane(tok, lb + j);
            v[j] = *reinterpret_cast<const float4*>(ltb + t * 1024u + voff);
        }
        #pragma unroll
        for (int j = 0; j < 8; ++j) {
            const float wl = lane_bcast_f(wn, lb + j);
            acc.x = fmaf(wl, v[j].x, acc.x);
            acc.y = fmaf(wl, v[j].y, acc.y);
            acc.z = fmaf(wl, v[j].z, acc.z);
            acc.w = fmaf(wl, v[j].w, acc.w);
        }
    }
    return acc;
}

__global__ __launch_bounds__(256) void encode_fused_f32(
    const int* __restrict__ xs, const int* __restrict__ mems,
    const int* __restrict__ ys, const int* __restrict__ cands,
    const float* __restrict__ lt, const float* __restrict__ freqs,
    float* __restrict__ lhs_raw, float* __restrict__ gsum,
    float* __restrict__ out_ys)
{
    __shared__ float s_xf[D_];
    __shared__ float s_an2;
    __shared__ float s_lred[D_];
    __shared__ float s_ered;

    const int wave = threadIdx.x >> 6;
    const int lane = threadIdx.x & 63;
    const int d0 = lane * 4;
    const unsigned voff = (unsigned)d0 * 4u;
    const char* ltb = (const char*)lt;
    const int rt0 = blockIdx.x * 4;
    const bool block_has_att = (rt0 <= M_);

    s_lred[threadIdx.x] = 0.f;
    if (threadIdx.x == 0) s_ered = 0.f;

    if (block_has_att && wave == 0) {
        const float4 xf = encode_row_f(xs, ltb, freqs, lane, voff);
        *reinterpret_cast<float4*>(&s_xf[d0]) = xf;
        const float an2 = wave_allreduce_sum(xf.x*xf.x + xf.y*xf.y + xf.z*xf.z + xf.w*xf.w);
        if (lane == 0) s_an2 = an2;
    }
    __syncthreads();

    const int rt = rt0 + wave;
    if (rt < NTASK) {
        const int* tok_ptr; float* dst = nullptr; bool has_att = false;
        if (rt == 0) { tok_ptr = xs; has_att = true; }
        else if (rt <= M_) { tok_ptr = mems + (size_t)(rt - 1) * L_; has_att = true; }
        else if (rt == M_ + 1) { tok_ptr = ys; dst = out_ys; }
        else {
            const int c = rt - (M_ + 2);
            tok_ptr = cands + (size_t)c * L_;
            dst = out_ys + (size_t)(c + 1) * D_;
        }
        const float4 acc = encode_row_f(tok_ptr, ltb, freqs, lane, voff);
        if (has_att) {
            const float4 xf = *reinterpret_cast<const float4*>(&s_xf[d0]);
            const float d = wave_allreduce_sum(acc.x*xf.x + acc.y*xf.y + acc.z*xf.z + acc.w*xf.w);
            const float q = wave_allreduce_sum(acc.x*acc.x + acc.y*acc.y + acc.z*acc.z + acc.w*acc.w);
            const float an = fmaxf(sqrtf(s_an2), 1e-8f);
            const float bn = fmaxf(sqrtf(q),  1e-8f);
            const float e = expf(d / (an * bn));
            atomicAdd(&s_lred[d0 + 0], e * acc.x);
            atomicAdd(&s_lred[d0 + 1], e * acc.y);
            atomicAdd(&s_lred[d0 + 2], e * acc.z);
            atomicAdd(&s_lred[d0 + 3], e * acc.w);
            if (lane == 0) atomicAdd(&s_ered, e);
        } else {
            *reinterpret_cast<float4*>(dst + d0) = acc;
        }
    }

    if (block_has_att) {
        __syncthreads();
        atomicAdd(&lhs_raw[threadIdx.x], s_lred[threadIdx.x]);
        if (threadIdx.x == 0) atomicAdd(gsum, s_ered);
    }
}

// ---------------------------------------------------------------------------
// K2: normalize lhs by the softmax denominator and tile into out_xs rows.
// ---------------------------------------------------------------------------
__global__ __launch_bounds__(256) void finalize_tile(
    const float* __restrict__ lhs_raw, const float* __restrict__ gsum,
    float* __restrict__ out_xs)
{
    const float val = lhs_raw[threadIdx.x] / gsum[0];
    for (int r = blockIdx.x; r < ROWS_MEMS; r += gridDim.x)
        out_xs[(size_t)r * D_ + threadIdx.x] = val;
}

extern "C" void kernel_launch(void* const* d_in, const int* in_sizes, int n_in,
                              void* d_out, int out_size, void* d_ws, size_t ws_size,
                              hipStream_t stream) {
    const int*   xs    = (const int*)d_in[0];
    const int*   mems  = (const int*)d_in[1];
    const int*   ys    = (const int*)d_in[2];
    const int*   cands = (const int*)d_in[3];
    const float* lt    = (const float*)d_in[4];
    const float* freqs = (const float*)d_in[5];

    float* out    = (float*)d_out;
    float* out_xs = out;                                   // [4097, 256]
    float* out_ys = out + (size_t)ROWS_MEMS * D_;          // [4097, 256]

    float* lhs_raw = (float*)d_ws;          // [256]
    float* gsum    = lhs_raw + D_;          // [1]
    float* g_xs    = gsum + 1;              // [257]: xf[256] + an2
    char*  lt_h    = (char*)d_ws + HALF_TBL_OFF;

    if (ws_size >= WS_NEEDED) {
        xs_pre<<<1, 64, 0, stream>>>(xs, lt, freqs, lhs_raw, gsum, g_xs);
        convert_lt<<<2048, 256, 0, stream>>>(
            (const float4*)lt, (uint2*)lt_h, (int)(LT_ELEMS / 4));
        encode_fused_h16<<<(NTASK + 3) / 4, 256, 0, stream>>>(
            xs, mems, ys, cands, lt_h, freqs, g_xs, lhs_raw, gsum, out_ys);
    } else {
        hipMemsetAsync(lhs_raw, 0, (D_ + 1) * sizeof(float), stream);
        encode_fused_f32<<<(NTASK + 3) / 4, 256, 0, stream>>>(
            xs, mems, ys, cands, lt, freqs, lhs_raw, gsum, out_ys);
    }
    finalize_tile<<<1024, 256, 0, stream>>>(lhs_raw, gsum, out_xs);
}

// Round 7
// 182.042 us; speedup vs baseline: 1.1869x; 1.1869x over previous
//
#include <hip/hip_runtime.h>

// Problem constants (match reference)
#define V_ 100000
#define D_ 256
#define M_ 4096
#define C_ 4096
#define L_ 32
#define ROWS_MEMS (M_ + 1)          // 4097 rows in mems_enc (mems + xs_emb)
#define NTASK (1 + M_ + 1 + C_)     // 8194 encode row-tasks

// Atomic-spread partial buffers: 262,400 global atomicAdds previously hit the
// SAME 256 dwords (~1025 serialized RMWs per address at one L2 slice). Spread
// over 32 buffers keyed by blockIdx&31 -> ~32 adds/address.
#define NBUF 32
#define BSTRIDE 260                  // 256 dims + esum@256, padded (1040 B, odd lines)
// ws float layout: part[NBUF*BSTRIDE] | g_xs[257] (xf[256], an2)

__device__ __forceinline__ float wave_allreduce_sum(float v) {
    #pragma unroll
    for (int off = 32; off >= 1; off >>= 1) v += __shfl_xor(v, off, 64);
    return v;
}

__device__ __forceinline__ float lane_bcast_f(float v, int l) {
    return __uint_as_float((unsigned)__builtin_amdgcn_readlane((int)__float_as_uint(v), l));
}

// fp32 gather encode: one wave per row, lane owns dims [4*lane, 4*lane+4).
// 8-deep scalarized batching (round-2 proven config: 63-64 us, VGPR 40).
__device__ __forceinline__ float4 encode_row_f(const int* __restrict__ tok_ptr,
                                               const char* __restrict__ ltb,
                                               const float* __restrict__ freqs,
                                               const int lane, const unsigned voff) {
    int tok = 0; float w = 0.f;
    if (lane < L_) { tok = tok_ptr[lane]; w = freqs[tok]; }
    const float s2 = wave_allreduce_sum(w * w);
    const float wn = w / sqrtf(s2);      // freqs > 0 -> s2 > 0

    float4 acc = make_float4(0.f, 0.f, 0.f, 0.f);
    #pragma unroll
    for (int lb = 0; lb < L_; lb += 8) {
        float4 v[8];
        #pragma unroll
        for (int j = 0; j < 8; ++j) {
            const unsigned t = (unsigned)__builtin_amdgcn_readlane(tok, lb + j);
            v[j] = *reinterpret_cast<const float4*>(ltb + t * 1024u + voff);
        }
        #pragma unroll
        for (int j = 0; j < 8; ++j) {
            const float wl = lane_bcast_f(wn, lb + j);
            acc.x = fmaf(wl, v[j].x, acc.x);
            acc.y = fmaf(wl, v[j].y, acc.y);
            acc.z = fmaf(wl, v[j].z, acc.z);
            acc.w = fmaf(wl, v[j].w, acc.w);
        }
    }
    return acc;
}

// ---------------------------------------------------------------------------
// K0: zero the partial buffers (replaces hipMemsetAsync) + one-wave fp32 xs
// encode -> g_xs[0..255], ||xs||^2 -> g_xs[256]. Hoists the xs prologue out
// of the 1025 att blocks.
// ---------------------------------------------------------------------------
__global__ __launch_bounds__(256) void xs_pre(
    const int* __restrict__ xs, const float* __restrict__ lt,
    const float* __restrict__ freqs, float* __restrict__ part,
    float* __restrict__ g_xs)
{
    for (int i = threadIdx.x; i < NBUF * BSTRIDE; i += 256) part[i] = 0.f;

    if (threadIdx.x < 64) {
        const int lane = threadIdx.x;
        const unsigned voff = (unsigned)lane * 16u;
        const float4 acc = encode_row_f(xs, (const char*)lt, freqs, lane, voff);
        *reinterpret_cast<float4*>(g_xs + lane * 4) = acc;
        const float an2 = wave_allreduce_sum(acc.x*acc.x + acc.y*acc.y +
                                             acc.z*acc.z + acc.w*acc.w);
        if (lane == 0) g_xs[256] = an2;
    }
}

// ---------------------------------------------------------------------------
// K1: fused encode + attention. One wave per row-task, 4 rows per block.
//   att rows: e = exp(cos(row, xs)) (cos in [-1,1], no max-sub needed);
//   accumulate e*row into LDS block-partial, then ONE global atomicAdd per
//   thread into partial buffer (blockIdx & 31) -- the atomic-spread A/B.
//   ys/cands rows: encode -> straight to out_ys.
// ---------------------------------------------------------------------------
__global__ __launch_bounds__(256) void encode_fused(
    const int* __restrict__ xs, const int* __restrict__ mems,
    const int* __restrict__ ys, const int* __restrict__ cands,
    const float* __restrict__ lt, const float* __restrict__ freqs,
    const float* __restrict__ g_xs,
    float* __restrict__ part,      // [NBUF][BSTRIDE]
    float* __restrict__ out_ys)    // d_out second half: [4097, 256]
{
    __shared__ float s_xf[D_];
    __shared__ float s_lred[D_];
    __shared__ float s_ered;
    __shared__ float s_an2;

    const int tid  = threadIdx.x;
    const int wave = tid >> 6;
    const int lane = tid & 63;
    const int d0 = lane * 4;
    const unsigned voff = (unsigned)d0 * 4u;
    const char* ltb = (const char*)lt;
    const int rt0 = blockIdx.x * 4;
    const bool block_has_att = (rt0 <= M_);   // blocks 0..1024 carry att rows

    s_lred[tid] = 0.f;
    if (tid == 0) s_ered = 0.f;
    if (block_has_att) {
        s_xf[tid] = g_xs[tid];               // precomputed fp32 xs encoding
        if (tid == 0) s_an2 = g_xs[256];
    }
    __syncthreads();

    const int rt = rt0 + wave;
    if (rt < NTASK) {
        const int* tok_ptr; float* dst = nullptr; bool has_att = false;
        if (rt == 0) {                       // xs row itself
            tok_ptr = xs; has_att = true;
        } else if (rt <= M_) {               // mems row rt-1
            tok_ptr = mems + (size_t)(rt - 1) * L_; has_att = true;
        } else if (rt == M_ + 1) {           // ys -> out_ys row 0
            tok_ptr = ys; dst = out_ys;
        } else {                             // cands -> out_ys rows 1..4096
            const int c = rt - (M_ + 2);
            tok_ptr = cands + (size_t)c * L_;
            dst = out_ys + (size_t)(c + 1) * D_;
        }

        const float4 acc = encode_row_f(tok_ptr, ltb, freqs, lane, voff);

        if (has_att) {
            const float4 xf = *reinterpret_cast<const float4*>(&s_xf[d0]);
            const float d = wave_allreduce_sum(acc.x*xf.x + acc.y*xf.y + acc.z*xf.z + acc.w*xf.w);
            const float q = wave_allreduce_sum(acc.x*acc.x + acc.y*acc.y + acc.z*acc.z + acc.w*acc.w);
            const float an = fmaxf(sqrtf(s_an2), 1e-8f);
            const float bn = fmaxf(sqrtf(q),  1e-8f);
            const float e = expf(d / (an * bn));     // same value on all lanes
            atomicAdd(&s_lred[d0 + 0], e * acc.x);   // LDS: 4-wave combine
            atomicAdd(&s_lred[d0 + 1], e * acc.y);
            atomicAdd(&s_lred[d0 + 2], e * acc.z);
            atomicAdd(&s_lred[d0 + 3], e * acc.w);
            if (lane == 0) atomicAdd(&s_ered, e);
        } else {
            *reinterpret_cast<float4*>(dst + d0) = acc;
        }
    }

    if (block_has_att) {
        __syncthreads();
        float* pb = part + (size_t)(blockIdx.x & (NBUF - 1)) * BSTRIDE;
        atomicAdd(&pb[tid], s_lred[tid]);            // ~32 adds/address now
        if (tid == 0) atomicAdd(&pb[256], s_ered);
    }
}

// ---------------------------------------------------------------------------
// K2: sum the 32 partial buffers, normalize by the softmax denominator, and
// tile into the 4097 out_xs rows. part[] is L2-hot (33 KB).
// ---------------------------------------------------------------------------
__global__ __launch_bounds__(256) void finalize_tile(
    const float* __restrict__ part, float* __restrict__ out_xs)
{
    float v = 0.f, g = 0.f;
    #pragma unroll
    for (int b = 0; b < NBUF; ++b) {
        v += part[b * BSTRIDE + threadIdx.x];
        g += part[b * BSTRIDE + 256];          // same addr across threads: broadcast
    }
    const float val = v / g;
    for (int r = blockIdx.x; r < ROWS_MEMS; r += gridDim.x)
        out_xs[(size_t)r * D_ + threadIdx.x] = val;
}

extern "C" void kernel_launch(void* const* d_in, const int* in_sizes, int n_in,
                              void* d_out, int out_size, void* d_ws, size_t ws_size,
                              hipStream_t stream) {
    const int*   xs    = (const int*)d_in[0];
    const int*   mems  = (const int*)d_in[1];
    const int*   ys    = (const int*)d_in[2];
    const int*   cands = (const int*)d_in[3];
    const float* lt    = (const float*)d_in[4];
    const float* freqs = (const float*)d_in[5];

    float* out    = (float*)d_out;
    float* out_xs = out;                                   // [4097, 256]
    float* out_ys = out + (size_t)ROWS_MEMS * D_;          // [4097, 256]

    float* part = (float*)d_ws;                            // [NBUF][BSTRIDE]
    float* g_xs = part + NBUF * BSTRIDE;                   // [257]

    xs_pre<<<1, 256, 0, stream>>>(xs, lt, freqs, part, g_xs);
    encode_fused<<<(NTASK + 3) / 4, 256, 0, stream>>>(
        xs, mems, ys, cands, lt, freqs, g_xs, part, out_ys);
    finalize_tile<<<1024, 256, 0, stream>>>(part, out_xs);
}